// Round 3
// baseline (112.867 us; speedup 1.0000x reference)
//
#include <hip/hip_runtime.h>
#include <math.h>

// HDCFactMemory: out = x + r_gate * sign(memory) * sign(x) * sign(role_read)
//   memory = cumsum_t( sign(x)*sign(role_write)*w_gate )
// Factored (exact: sign(role_write) = ±1/0 multiplies out of the cumsum):
//   out = x + r_gate[b,t] * K[d] * sign(S[b,t,d]) * sign(x[b,t,d])
//   K[d] = sign(role_write[d])*sign(role_read[d])
//   S[b,t,d] = sum_{t'<=t} sign(x[b,t',d]) * w_gate[b,t']
// Sign-determining arithmetic (gates, scan) in f64 to match the np-f64 ref;
// output combine in f32 (validation is bf16-quantized, threshold 0.119).
//
// R3 structure: K12 fuses gates+chunk-partials (x HBM-read once, slab reread
// is cache-warm); K2.5 precomputes chunk prefixes (kills the O(c) per-block
// prefix loop); K3 scans in-chunk and writes out (x read is L3-resident).

#define T_LEN 4096
#define D_LEN 4096
#define TC 32              // timesteps per chunk
#define NC (T_LEN / TC)    // 128 chunks
#define D4 (D_LEN / 4)     // 1024 float4 per row

__device__ __forceinline__ float fsgn(float v) {
    return (v > 0.f) ? 1.f : ((v < 0.f) ? -1.f : 0.f);
}
__device__ __forceinline__ double dsgn(double v) {
    return (v > 0.) ? 1. : ((v < 0.) ? -1. : 0.);
}

// ---- K12: per-chunk gates (f64 row dots) + per-column chunk partials ----
// block = (chunk c, batch b), 512 threads. Phase A: 16 threads per row
// compute both dots; phase B: re-traverse slab (cache-warm) for partials.
__global__ __launch_bounds__(512) void gates_partial_kernel(
    const float* __restrict__ x,
    const float* __restrict__ wg_w, const float* __restrict__ wg_b,
    const float* __restrict__ rg_w, const float* __restrict__ rg_b,
    double* __restrict__ wgate, double* __restrict__ rgate,
    double* __restrict__ partial)
{
    const int c = blockIdx.x;
    const int b = blockIdx.y;
    const int tid = threadIdx.x;

    __shared__ double wsm[TC];

    // ---- phase A: gates for rows [c*TC, (c+1)*TC) ----
    const int r   = tid >> 4;          // row within chunk (32 rows)
    const int sub = tid & 15;          // 16 threads per row
    const float4* x4 = (const float4*)x;
    const float4* w4 = (const float4*)wg_w;
    const float4* g4 = (const float4*)rg_w;
    const size_t rowbase = ((size_t)b * T_LEN + (size_t)c * TC + r) * D4;

    double dw = 0., dr = 0.;
    #pragma unroll 4
    for (int k = sub; k < D4; k += 16) {
        float4 v = x4[rowbase + k];
        float4 a = w4[k];
        float4 g = g4[k];
        dw += (double)v.x * a.x + (double)v.y * a.y
            + (double)v.z * a.z + (double)v.w * a.w;
        dr += (double)v.x * g.x + (double)v.y * g.y
            + (double)v.z * g.z + (double)v.w * g.w;
    }
    #pragma unroll
    for (int off = 8; off >= 1; off >>= 1) {
        dw += __shfl_down(dw, off, 16);
        dr += __shfl_down(dr, off, 16);
    }
    if (sub == 0) {
        double wg = 1. / (1. + exp(-(dw + (double)wg_b[0])));
        double rg = 1. / (1. + exp(-(dr + (double)rg_b[0])));
        wsm[r] = wg;
        const int row = b * T_LEN + c * TC + r;
        wgate[row] = wg;
        rgate[row] = rg;
    }
    __syncthreads();

    // ---- phase B: per-column partial sums of sign(x)*w_gate over the chunk ----
    const size_t slab = ((size_t)b * T_LEN + (size_t)c * TC) * D4;
    for (int dd = tid; dd < D4; dd += 512) {
        double ax = 0., ay = 0., az = 0., aw = 0.;
        #pragma unroll 8
        for (int i = 0; i < TC; ++i) {
            float4 v = x4[slab + (size_t)i * D4 + dd];
            double w = wsm[i];
            ax += (double)fsgn(v.x) * w;
            ay += (double)fsgn(v.y) * w;
            az += (double)fsgn(v.z) * w;
            aw += (double)fsgn(v.w) * w;
        }
        double* p = partial + (((size_t)(b * NC + c)) * D4 + dd) * 4;
        p[0] = ax; p[1] = ay; p[2] = az; p[3] = aw;
    }
}

// ---- K2.5: exclusive prefix over chunks, per (b, d) column ----
// m in [0, 4096): flat f64 column index within a chunk record.
__global__ __launch_bounds__(256) void prefix_kernel(
    const double* __restrict__ partial, double* __restrict__ prefix)
{
    const int m = blockIdx.x * 256 + threadIdx.x;
    const int b = blockIdx.y;
    double s = 0.;
    #pragma unroll 4
    for (int c = 0; c < NC; ++c) {
        size_t idx = ((size_t)(b * NC + c)) * (D4 * 4) + m;
        double v = partial[idx];
        prefix[idx] = s;
        s += v;
    }
}

// ---- K3: in-chunk sequential f64 scan + f32 output ----
__global__ __launch_bounds__(256) void final_kernel(
    const float* __restrict__ x,
    const double* __restrict__ wgate, const double* __restrict__ rgate,
    const float* __restrict__ role_w, const float* __restrict__ role_r,
    const double* __restrict__ prefix,
    float* __restrict__ out)
{
    const int b = blockIdx.z;
    const int c = blockIdx.y;
    const int d4 = blockIdx.x * 256 + threadIdx.x;

    __shared__ double wsm[TC];
    __shared__ float rsm[TC];
    if (threadIdx.x < TC) {
        wsm[threadIdx.x] = wgate[b * T_LEN + c * TC + threadIdx.x];
        rsm[threadIdx.x] = (float)rgate[b * T_LEN + c * TC + threadIdx.x];
    }
    __syncthreads();

    float4 rw = ((const float4*)role_w)[d4];
    float4 rr = ((const float4*)role_r)[d4];
    const float kx = fsgn(rw.x) * fsgn(rr.x);
    const float ky = fsgn(rw.y) * fsgn(rr.y);
    const float kz = fsgn(rw.z) * fsgn(rr.z);
    const float kw = fsgn(rw.w) * fsgn(rr.w);

    const double* p = prefix + (((size_t)(b * NC + c)) * D4 + d4) * 4;
    double ax = p[0], ay = p[1], az = p[2], aw = p[3];

    const float4* x4 = (const float4*)x;
    float4* o4 = (float4*)out;
    const size_t slab = ((size_t)b * T_LEN + (size_t)c * TC) * D4 + d4;

    #pragma unroll 4
    for (int i = 0; i < TC; ++i) {
        float4 v = x4[slab + (size_t)i * D4];
        double w = wsm[i];
        float rf = rsm[i];
        float sx = fsgn(v.x), sy = fsgn(v.y), sz = fsgn(v.z), sw2 = fsgn(v.w);
        ax += (double)sx * w; ay += (double)sy * w;
        az += (double)sz * w; aw += (double)sw2 * w;
        float4 o;
        o.x = v.x + rf * kx * (float)dsgn(ax) * sx;
        o.y = v.y + rf * ky * (float)dsgn(ay) * sy;
        o.z = v.z + rf * kz * (float)dsgn(az) * sz;
        o.w = v.w + rf * kw * (float)dsgn(aw) * sw2;
        o4[slab + (size_t)i * D4] = o;
    }
}

extern "C" void kernel_launch(void* const* d_in, const int* in_sizes, int n_in,
                              void* d_out, int out_size, void* d_ws, size_t ws_size,
                              hipStream_t stream) {
    const float* x      = (const float*)d_in[0];
    const float* role_w = (const float*)d_in[1];
    const float* role_r = (const float*)d_in[2];
    const float* wg_w   = (const float*)d_in[3];
    const float* wg_b   = (const float*)d_in[4];
    const float* rg_w   = (const float*)d_in[5];
    const float* rg_b   = (const float*)d_in[6];
    float* out = (float*)d_out;

    const int B = in_sizes[0] / (T_LEN * D_LEN);   // = 2
    const int BT = B * T_LEN;

    // ws layout (f64): wgate[BT], rgate[BT], partial[B*NC*4096], prefix[same]
    double* wgate   = (double*)d_ws;
    double* rgate   = wgate + BT;
    double* partial = rgate + BT;
    double* prefix  = partial + (size_t)B * NC * (D4 * 4);   // total ~16.9 MB

    dim3 g12(NC, B);
    gates_partial_kernel<<<g12, 512, 0, stream>>>(
        x, wg_w, wg_b, rg_w, rg_b, wgate, rgate, partial);

    dim3 g25((D4 * 4) / 256, B);   // (16, 2)
    prefix_kernel<<<g25, 256, 0, stream>>>(partial, prefix);

    dim3 g3(D4 / 256, NC, B);      // (4, 128, 2)
    final_kernel<<<g3, 256, 0, stream>>>(
        x, wgate, rgate, role_w, role_r, prefix, out);
}

// Round 4
// 103.571 us; speedup vs baseline: 1.0898x; 1.0898x over previous
//
#include <hip/hip_runtime.h>
#include <math.h>

// HDCFactMemory: out = x + r_gate * sign(memory) * sign(x) * sign(role_read)
//   memory = cumsum_t( sign(x)*sign(role_write)*w_gate )
// Factored (exact: sign(role_write) = ±1/0 multiplies out of the cumsum):
//   out = x + r_gate[b,t] * K[d] * sign(S[b,t,d]) * sign(x[b,t,d])
//   S[b,t,d] = sum_{t'<=t} sign(x[b,t',d]) * w_gate[b,t']
// Sign-determining arithmetic (gates, scan) in f64 (np-f64 reference).
//
// R4 structure (kill redundant x passes):
//   K1  gates + 2-bit sign(x) pack        : x 134MB HBM read, 8.4MB write
//   K2a chunk partials from packed signs  : 8.4MB read (was a full x pass)
//   K2b exclusive chunk prefix            : 4.2MB r/w
//   K3  in-chunk rescan + output          : x re-read (L3-warm) + 134MB write

#define T_LEN 4096
#define D_LEN 4096
#define TC 64              // timesteps per chunk
#define NC (T_LEN / TC)    // 64 chunks
#define D4 (D_LEN / 4)     // 1024 float4 per row (also packed bytes per row)

__device__ __forceinline__ float fsgn(float v) {
    return (v > 0.f) ? 1.f : ((v < 0.f) ? -1.f : 0.f);
}
__device__ __forceinline__ double dsgn(double v) {
    return (v > 0.) ? 1. : ((v < 0.) ? -1. : 0.);
}
__device__ __forceinline__ unsigned scode(float v) {   // 0:neg 1:zero 2:pos
    return (v > 0.f) ? 2u : ((v < 0.f) ? 0u : 1u);
}

// ---- K1: per-row gates (f64 dots) + 2-bit sign pack ----
__global__ __launch_bounds__(256) void gates_pack_kernel(
    const float* __restrict__ x,
    const float* __restrict__ wg_w, const float* __restrict__ wg_b,
    const float* __restrict__ rg_w, const float* __restrict__ rg_b,
    double* __restrict__ wgate, double* __restrict__ rgate,
    unsigned char* __restrict__ packed)
{
    const int row = blockIdx.x;                  // b*T + t
    const float4* xr = (const float4*)(x + (size_t)row * D_LEN);
    const float4* w4 = (const float4*)wg_w;
    const float4* r4 = (const float4*)rg_w;
    unsigned char* pr = packed + (size_t)row * D4;

    double dw = 0., dr = 0.;
    #pragma unroll 4
    for (int i = threadIdx.x; i < D4; i += 256) {
        float4 v = xr[i];
        float4 a = w4[i];
        float4 g = r4[i];
        dw += (double)v.x * a.x + (double)v.y * a.y
            + (double)v.z * a.z + (double)v.w * a.w;
        dr += (double)v.x * g.x + (double)v.y * g.y
            + (double)v.z * g.z + (double)v.w * g.w;
        pr[i] = (unsigned char)(scode(v.x) | (scode(v.y) << 2)
                              | (scode(v.z) << 4) | (scode(v.w) << 6));
    }
    for (int off = 32; off > 0; off >>= 1) {
        dw += __shfl_down(dw, off);
        dr += __shfl_down(dr, off);
    }
    __shared__ double sdw[4], sdr[4];
    const int wid = threadIdx.x >> 6;
    if ((threadIdx.x & 63) == 0) { sdw[wid] = dw; sdr[wid] = dr; }
    __syncthreads();
    if (threadIdx.x == 0) {
        double zw = sdw[0] + sdw[1] + sdw[2] + sdw[3] + (double)wg_b[0];
        double zr = sdr[0] + sdr[1] + sdr[2] + sdr[3] + (double)rg_b[0];
        wgate[row] = 1. / (1. + exp(-zw));
        rgate[row] = 1. / (1. + exp(-zr));
    }
}

// ---- K2a: per-chunk column partials from packed signs ----
// grid (NC, B), 256 threads; thread owns 16 consecutive f32 columns.
__global__ __launch_bounds__(256) void partial_kernel(
    const unsigned char* __restrict__ packed,
    const double* __restrict__ wgate,
    double* __restrict__ partial)
{
    const int c = blockIdx.x;
    const int b = blockIdx.y;
    const int tid = threadIdx.x;

    __shared__ double wsm[TC];
    if (tid < TC) wsm[tid] = wgate[b * T_LEN + c * TC + tid];
    __syncthreads();

    double acc[16];
    #pragma unroll
    for (int k = 0; k < 16; ++k) acc[k] = 0.;

    const size_t rowbase = ((size_t)b * T_LEN + (size_t)c * TC) * D4;
    for (int t = 0; t < TC; ++t) {
        unsigned pk = *(const unsigned*)(packed + rowbase + (size_t)t * D4 + tid * 4);
        double w = wsm[t];
        #pragma unroll
        for (int k = 0; k < 16; ++k) {
            int code = (int)((pk >> (2 * k)) & 3u) - 1;   // -1, 0, +1
            acc[k] += (double)code * w;
        }
    }
    double* p = partial + ((size_t)(b * NC + c)) * D_LEN + tid * 16;
    #pragma unroll
    for (int k = 0; k < 16; ++k) p[k] = acc[k];
}

// ---- K2b: exclusive prefix over chunks per column ----
__global__ __launch_bounds__(256) void prefix_kernel(
    const double* __restrict__ partial, double* __restrict__ prefix)
{
    const int m = blockIdx.x * 256 + threadIdx.x;   // column in [0, 4096)
    const int b = blockIdx.y;
    double s = 0.;
    for (int c = 0; c < NC; ++c) {
        size_t idx = ((size_t)(b * NC + c)) * D_LEN + m;
        double v = partial[idx];
        prefix[idx] = s;
        s += v;
    }
}

// ---- K3: in-chunk sequential f64 rescan + f32 output ----
__global__ __launch_bounds__(256) void final_kernel(
    const float* __restrict__ x,
    const double* __restrict__ wgate, const double* __restrict__ rgate,
    const float* __restrict__ role_w, const float* __restrict__ role_r,
    const double* __restrict__ prefix,
    float* __restrict__ out)
{
    const int b = blockIdx.z;
    const int c = blockIdx.y;
    const int d4 = blockIdx.x * 256 + threadIdx.x;

    __shared__ double wsm[TC];
    __shared__ float rsm[TC];
    if (threadIdx.x < TC) {
        wsm[threadIdx.x] = wgate[b * T_LEN + c * TC + threadIdx.x];
        rsm[threadIdx.x] = (float)rgate[b * T_LEN + c * TC + threadIdx.x];
    }
    __syncthreads();

    float4 rw = ((const float4*)role_w)[d4];
    float4 rr = ((const float4*)role_r)[d4];
    const float kx = fsgn(rw.x) * fsgn(rr.x);
    const float ky = fsgn(rw.y) * fsgn(rr.y);
    const float kz = fsgn(rw.z) * fsgn(rr.z);
    const float kw = fsgn(rw.w) * fsgn(rr.w);

    const double* p = prefix + ((size_t)(b * NC + c)) * D_LEN + d4 * 4;
    double ax = p[0], ay = p[1], az = p[2], aw = p[3];

    const float4* x4 = (const float4*)x;
    float4* o4 = (float4*)out;
    const size_t slab = ((size_t)b * T_LEN + (size_t)c * TC) * D4 + d4;

    #pragma unroll 4
    for (int i = 0; i < TC; ++i) {
        float4 v = x4[slab + (size_t)i * D4];
        double w = wsm[i];
        float rf = rsm[i];
        float sx = fsgn(v.x), sy = fsgn(v.y), sz = fsgn(v.z), sw2 = fsgn(v.w);
        ax += (double)sx * w; ay += (double)sy * w;
        az += (double)sz * w; aw += (double)sw2 * w;
        float4 o;
        o.x = v.x + rf * kx * (float)dsgn(ax) * sx;
        o.y = v.y + rf * ky * (float)dsgn(ay) * sy;
        o.z = v.z + rf * kz * (float)dsgn(az) * sz;
        o.w = v.w + rf * kw * (float)dsgn(aw) * sw2;
        o4[slab + (size_t)i * D4] = o;
    }
}

extern "C" void kernel_launch(void* const* d_in, const int* in_sizes, int n_in,
                              void* d_out, int out_size, void* d_ws, size_t ws_size,
                              hipStream_t stream) {
    const float* x      = (const float*)d_in[0];
    const float* role_w = (const float*)d_in[1];
    const float* role_r = (const float*)d_in[2];
    const float* wg_w   = (const float*)d_in[3];
    const float* wg_b   = (const float*)d_in[4];
    const float* rg_w   = (const float*)d_in[5];
    const float* rg_b   = (const float*)d_in[6];
    float* out = (float*)d_out;

    const int B = in_sizes[0] / (T_LEN * D_LEN);   // = 2
    const int BT = B * T_LEN;

    // ws layout: f64 arrays first (alignment), then packed bytes.
    double* wgate   = (double*)d_ws;                           // BT
    double* rgate   = wgate + BT;                              // BT
    double* partial = rgate + BT;                              // B*NC*D
    double* prefix  = partial + (size_t)B * NC * D_LEN;        // B*NC*D
    unsigned char* packed = (unsigned char*)(prefix + (size_t)B * NC * D_LEN);
                                                               // BT*D4 bytes

    gates_pack_kernel<<<BT, 256, 0, stream>>>(
        x, wg_w, wg_b, rg_w, rg_b, wgate, rgate, packed);

    dim3 g2a(NC, B);               // (64, 2)
    partial_kernel<<<g2a, 256, 0, stream>>>(packed, wgate, partial);

    dim3 g2b(D_LEN / 256, B);      // (16, 2)
    prefix_kernel<<<g2b, 256, 0, stream>>>(partial, prefix);

    dim3 g3(D4 / 256, NC, B);      // (4, 64, 2)
    final_kernel<<<g3, 256, 0, stream>>>(
        x, wgate, rgate, role_w, role_r, prefix, out);
}

// Round 6
// 95.611 us; speedup vs baseline: 1.1805x; 1.0833x over previous
//
#include <hip/hip_runtime.h>
#include <math.h>

// HDCFactMemory: out = x + r_gate * sign(memory) * sign(x) * sign(role_read)
//   memory = cumsum_t( sign(x)*sign(role_write)*w_gate )
// Factored (exact: sign(role_write) = ±1/0 multiplies out of the cumsum):
//   out = x + r_gate[b,t] * K[d] * sign(S[b,t,d]) * sign(x[b,t,d])
//   S[b,t,d] = sum_{t'<=t} sign(x[b,t',d]) * w_gate[b,t']
// Sign-determining arithmetic (gates, scan) in f64 (np-f64 reference).
//
// R6 = R5 with the NT-store compile fix: __builtin_nontemporal_store needs a
// native vector type, not HIP_vector_type. out is never re-read -> NT stores
// keep x L3-resident during K3's re-read (134MB x + 17MB scratch < 256MB LLC).

#define T_LEN 4096
#define D_LEN 4096
#define TC 32              // timesteps per chunk
#define NC (T_LEN / TC)    // 128 chunks
#define D4 (D_LEN / 4)     // 1024 float4 per row (also packed bytes per row)

typedef float nfloat4 __attribute__((ext_vector_type(4)));   // native vec for NT store

__device__ __forceinline__ float fsgn(float v) {
    return (v > 0.f) ? 1.f : ((v < 0.f) ? -1.f : 0.f);
}
__device__ __forceinline__ double dsgn(double v) {
    return (v > 0.) ? 1. : ((v < 0.) ? -1. : 0.);
}
__device__ __forceinline__ unsigned scode(float v) {   // 0:neg 1:zero 2:pos
    return (v > 0.f) ? 2u : ((v < 0.f) ? 0u : 1u);
}

// ---- K1: per-row gates (f64 dots) + 2-bit sign pack ----
__global__ __launch_bounds__(256) void gates_pack_kernel(
    const float* __restrict__ x,
    const float* __restrict__ wg_w, const float* __restrict__ wg_b,
    const float* __restrict__ rg_w, const float* __restrict__ rg_b,
    double* __restrict__ wgate, double* __restrict__ rgate,
    unsigned char* __restrict__ packed)
{
    const int row = blockIdx.x;                  // b*T + t
    const float4* xr = (const float4*)(x + (size_t)row * D_LEN);
    const float4* w4 = (const float4*)wg_w;
    const float4* r4 = (const float4*)rg_w;
    unsigned char* pr = packed + (size_t)row * D4;

    double dw = 0., dr = 0.;
    #pragma unroll 4
    for (int i = threadIdx.x; i < D4; i += 256) {
        float4 v = xr[i];
        float4 a = w4[i];
        float4 g = r4[i];
        dw += (double)v.x * a.x + (double)v.y * a.y
            + (double)v.z * a.z + (double)v.w * a.w;
        dr += (double)v.x * g.x + (double)v.y * g.y
            + (double)v.z * g.z + (double)v.w * g.w;
        pr[i] = (unsigned char)(scode(v.x) | (scode(v.y) << 2)
                              | (scode(v.z) << 4) | (scode(v.w) << 6));
    }
    for (int off = 32; off > 0; off >>= 1) {
        dw += __shfl_down(dw, off);
        dr += __shfl_down(dr, off);
    }
    __shared__ double sdw[4], sdr[4];
    const int wid = threadIdx.x >> 6;
    if ((threadIdx.x & 63) == 0) { sdw[wid] = dw; sdr[wid] = dr; }
    __syncthreads();
    if (threadIdx.x == 0) {
        double zw = sdw[0] + sdw[1] + sdw[2] + sdw[3] + (double)wg_b[0];
        double zr = sdr[0] + sdr[1] + sdr[2] + sdr[3] + (double)rg_b[0];
        wgate[row] = 1. / (1. + exp(-zw));
        rgate[row] = 1. / (1. + exp(-zr));
    }
}

// ---- K2a: per-chunk column partials from packed signs ----
__global__ __launch_bounds__(256) void partial_kernel(
    const unsigned char* __restrict__ packed,
    const double* __restrict__ wgate,
    double* __restrict__ partial)
{
    const int c = blockIdx.x;
    const int b = blockIdx.y;
    const int tid = threadIdx.x;

    __shared__ double wsm[TC];
    if (tid < TC) wsm[tid] = wgate[b * T_LEN + c * TC + tid];
    __syncthreads();

    double acc[16];
    #pragma unroll
    for (int k = 0; k < 16; ++k) acc[k] = 0.;

    const size_t rowbase = ((size_t)b * T_LEN + (size_t)c * TC) * D4;
    for (int t = 0; t < TC; ++t) {
        unsigned pk = *(const unsigned*)(packed + rowbase + (size_t)t * D4 + tid * 4);
        double w = wsm[t];
        #pragma unroll
        for (int k = 0; k < 16; ++k) {
            int code = (int)((pk >> (2 * k)) & 3u) - 1;   // -1, 0, +1
            acc[k] += (double)code * w;
        }
    }
    double* p = partial + ((size_t)(b * NC + c)) * D_LEN + tid * 16;
    #pragma unroll
    for (int k = 0; k < 16; ++k) p[k] = acc[k];
}

// ---- K2b: exclusive prefix over chunks per column ----
__global__ __launch_bounds__(256) void prefix_kernel(
    const double* __restrict__ partial, double* __restrict__ prefix)
{
    const int m = blockIdx.x * 256 + threadIdx.x;   // column in [0, 4096)
    const int b = blockIdx.y;
    double s = 0.;
    for (int c = 0; c < NC; ++c) {
        size_t idx = ((size_t)(b * NC + c)) * D_LEN + m;
        double v = partial[idx];
        prefix[idx] = s;
        s += v;
    }
}

// ---- K3: in-chunk sequential f64 rescan + f32 output (NT stores) ----
__global__ __launch_bounds__(256) void final_kernel(
    const float* __restrict__ x,
    const double* __restrict__ wgate, const double* __restrict__ rgate,
    const float* __restrict__ role_w, const float* __restrict__ role_r,
    const double* __restrict__ prefix,
    float* __restrict__ out)
{
    const int b = blockIdx.z;
    const int c = blockIdx.y;
    const int d4 = blockIdx.x * 256 + threadIdx.x;

    __shared__ double wsm[TC];
    __shared__ float rsm[TC];
    if (threadIdx.x < TC) {
        wsm[threadIdx.x] = wgate[b * T_LEN + c * TC + threadIdx.x];
        rsm[threadIdx.x] = (float)rgate[b * T_LEN + c * TC + threadIdx.x];
    }
    __syncthreads();

    float4 rw = ((const float4*)role_w)[d4];
    float4 rr = ((const float4*)role_r)[d4];
    const float kx = fsgn(rw.x) * fsgn(rr.x);
    const float ky = fsgn(rw.y) * fsgn(rr.y);
    const float kz = fsgn(rw.z) * fsgn(rr.z);
    const float kw = fsgn(rw.w) * fsgn(rr.w);

    const double* p = prefix + ((size_t)(b * NC + c)) * D_LEN + d4 * 4;
    double ax = p[0], ay = p[1], az = p[2], aw = p[3];

    const float4* x4 = (const float4*)x;
    nfloat4* o4 = (nfloat4*)out;
    const size_t slab = ((size_t)b * T_LEN + (size_t)c * TC) * D4 + d4;

    #pragma unroll 4
    for (int i = 0; i < TC; ++i) {
        float4 v = x4[slab + (size_t)i * D4];
        double w = wsm[i];
        float rf = rsm[i];
        float sx = fsgn(v.x), sy = fsgn(v.y), sz = fsgn(v.z), sw2 = fsgn(v.w);
        ax += (double)sx * w; ay += (double)sy * w;
        az += (double)sz * w; aw += (double)sw2 * w;
        nfloat4 o;
        o.x = v.x + rf * kx * (float)dsgn(ax) * sx;
        o.y = v.y + rf * ky * (float)dsgn(ay) * sy;
        o.z = v.z + rf * kz * (float)dsgn(az) * sz;
        o.w = v.w + rf * kw * (float)dsgn(aw) * sw2;
        __builtin_nontemporal_store(o, &o4[slab + (size_t)i * D4]);
    }
}

extern "C" void kernel_launch(void* const* d_in, const int* in_sizes, int n_in,
                              void* d_out, int out_size, void* d_ws, size_t ws_size,
                              hipStream_t stream) {
    const float* x      = (const float*)d_in[0];
    const float* role_w = (const float*)d_in[1];
    const float* role_r = (const float*)d_in[2];
    const float* wg_w   = (const float*)d_in[3];
    const float* wg_b   = (const float*)d_in[4];
    const float* rg_w   = (const float*)d_in[5];
    const float* rg_b   = (const float*)d_in[6];
    float* out = (float*)d_out;

    const int B = in_sizes[0] / (T_LEN * D_LEN);   // = 2
    const int BT = B * T_LEN;

    // ws layout: f64 arrays first (alignment), then packed bytes.
    double* wgate   = (double*)d_ws;                           // BT
    double* rgate   = wgate + BT;                              // BT
    double* partial = rgate + BT;                              // B*NC*D
    double* prefix  = partial + (size_t)B * NC * D_LEN;        // B*NC*D
    unsigned char* packed = (unsigned char*)(prefix + (size_t)B * NC * D_LEN);
                                                               // BT*D4 bytes

    gates_pack_kernel<<<BT, 256, 0, stream>>>(
        x, wg_w, wg_b, rg_w, rg_b, wgate, rgate, packed);

    dim3 g2a(NC, B);               // (128, 2)
    partial_kernel<<<g2a, 256, 0, stream>>>(packed, wgate, partial);

    dim3 g2b(D_LEN / 256, B);      // (16, 2)
    prefix_kernel<<<g2b, 256, 0, stream>>>(partial, prefix);

    dim3 g3(D4 / 256, NC, B);      // (4, 128, 2)
    final_kernel<<<g3, 256, 0, stream>>>(
        x, wgate, rgate, role_w, role_r, prefix, out);
}